// Round 8
// baseline (345.374 us; speedup 1.0000x reference)
//
#include <hip/hip_runtime.h>
#include <hip/hip_bf16.h>

// Problem constants
#define B_   2
#define S_   2048
#define C_   2048
#define H_   16
#define DH   128
#define C3   (3 * C_)

typedef __attribute__((ext_vector_type(8))) short short8;
typedef __attribute__((ext_vector_type(4))) float floatx4;

__device__ __forceinline__ void gload16(const void* g, void* l) {
  __builtin_amdgcn_global_load_lds(
      (const __attribute__((address_space(1))) unsigned int*)g,
      (__attribute__((address_space(3))) unsigned int*)l, 16, 0, 0);
}

__device__ __forceinline__ unsigned pk_bf16(float a, float b) {
  union { __hip_bfloat16 h; unsigned short u; } ua, ub;
  ua.h = __float2bfloat16(a); ub.h = __float2bfloat16(b);
  return (unsigned)ua.u | ((unsigned)ub.u << 16);
}

__device__ __forceinline__ float bf2f(short u) {
  union { unsigned u; float f; } t;
  t.u = ((unsigned)(unsigned short)u) << 16;
  return t.f;
}
__device__ __forceinline__ short f2bf(float f) {
  union { __hip_bfloat16 h; short s; } t;
  t.h = __float2bfloat16(f);
  return t.s;
}

// ---------------- transpose + cast (VECTORIZED r8): in[R][Cc] f32 -> out[Cc][R] bf16 ----------------
// float4 loads (16B/lane), uint2 stores (8B/lane). LDS banks checked: both phases <=2-way (free).
__device__ __forceinline__ void transpose_cast_dev(
    const float* __restrict__ in, __hip_bfloat16* __restrict__ out,
    int R, int Cc, int c0, int r0, int tid, float (*tile)[33]) {
  int row = tid >> 3, col4 = tid & 7;  // 32 rows x 8 float4
  float4 v = *(const float4*)&in[(size_t)(r0 + row) * Cc + c0 + col4 * 4];
  tile[row][col4 * 4 + 0] = v.x;
  tile[row][col4 * 4 + 1] = v.y;
  tile[row][col4 * 4 + 2] = v.z;
  tile[row][col4 * 4 + 3] = v.w;
  __syncthreads();
  int c = tid >> 3, r4 = tid & 7;      // 32 cols x 8 row-quads
  union { __hip_bfloat16 b[4]; uint2 u; } t;
#pragma unroll
  for (int e = 0; e < 4; ++e) t.b[e] = __float2bfloat16(tile[r4 * 4 + e][c]);
  *(uint2*)&out[(size_t)(c0 + c) * R + r0 + r4 * 4] = t.u;
}

// ---------------- fused pre-GEMM1: cast x -> bf16  +  transpose Wqkv ----------------
__global__ __launch_bounds__(256) void pre_kernel(
    const float* __restrict__ x, __hip_bfloat16* __restrict__ xb,
    const float* __restrict__ Wqkv, __hip_bfloat16* __restrict__ WqkvT) {
  __shared__ float tile[32][33];
  const int bid = blockIdx.x, tid = threadIdx.x;
  if (bid < 8192) {
    int i = bid * 256 + tid;  // < 2097152 = (4096*2048)/4 exactly
    float4 v = ((const float4*)x)[i];
    union { __hip_bfloat16 b[4]; uint2 u; } t;
    t.b[0] = __float2bfloat16(v.x);
    t.b[1] = __float2bfloat16(v.y);
    t.b[2] = __float2bfloat16(v.z);
    t.b[3] = __float2bfloat16(v.w);
    ((uint2*)xb)[i] = t.u;
  } else {
    int tb = bid - 8192;             // 12288 tiles: 192 x 64
    int bx = tb % 192, by = tb / 192;
    transpose_cast_dev(Wqkv, WqkvT, 2048, 6144, bx * 32, by * 32, tid, tile);
  }
}

// ---------------- sync macros (rule: sched_barrier after every asm wait / barrier) ----------------
#define S_VMCNT2 do { asm volatile("s_waitcnt vmcnt(2)" ::: "memory"); \
                      __builtin_amdgcn_sched_barrier(0); } while (0)
#define S_LGKM0  do { asm volatile("s_waitcnt lgkmcnt(0)" ::: "memory"); \
                      __builtin_amdgcn_sched_barrier(0); } while (0)
#define S_BAR    do { __builtin_amdgcn_s_barrier(); \
                      __builtin_amdgcn_sched_barrier(0); } while (0)

// ---------------- GEMM1: 256x192, BK=64, wave tile 128x48, 8-phase counted-vmcnt ----------------
// FROZEN at the r3/r4-proven structure (96.4 us, MfmaUtil 46, 0 bank conflicts).
// r5 (BM512 min-sync) and r6 (m201 barrier order) both regressed; see post-mortems.

#define RD_A4(dst, buf, mh, sl)                                                          \
  do {                                                                                   \
    const __hip_bfloat16* base_ =                                                        \
        lds + (buf) * 28672 + (wm * 128 + (mh) * 64 + lr) * 64 + ((sl) ? sw1 : sw0);     \
    _Pragma("unroll") for (int i_ = 0; i_ < 4; ++i_)                                     \
        dst[i_] = *(const short8*)(base_ + i_ * 1024);                                   \
  } while (0)

#define RD_B3(dst, buf, sl)                                                              \
  do {                                                                                   \
    const __hip_bfloat16* base_ =                                                        \
        lds + (buf) * 28672 + 16384 + (wn * 48 + lr) * 64 + ((sl) ? sw1 : sw0);          \
    _Pragma("unroll") for (int j_ = 0; j_ < 3; ++j_)                                     \
        dst[j_] = *(const short8*)(base_ + j_ * 1024);                                   \
  } while (0)

#define MFG(afp, bfp, mh)                                                                \
  do {                                                                                   \
    __builtin_amdgcn_s_setprio(1);                                                       \
    _Pragma("unroll") for (int i_ = 0; i_ < 4; ++i_)                                     \
    _Pragma("unroll") for (int j_ = 0; j_ < 3; ++j_)                                     \
        acc[(mh) * 4 + i_][j_] = __builtin_amdgcn_mfma_f32_16x16x32_bf16(                \
            afp[i_], bfp[j_], acc[(mh) * 4 + i_][j_], 0, 0, 0);                          \
    __builtin_amdgcn_s_setprio(0);                                                       \
  } while (0)

__global__ __launch_bounds__(512, 2) void gemm1_kernel(
    const __hip_bfloat16* __restrict__ A, const __hip_bfloat16* __restrict__ Bt,
    __hip_bfloat16* __restrict__ Cp) {
  const int K = 2048;
  __shared__ __hip_bfloat16 lds[2 * 28672];  // 2 x (A 16384 + B 12288) elems
  const int tid = threadIdx.x;
  const int lane = tid & 63, wv = tid >> 6;
  const int wm = wv >> 2, wn = wv & 3;  // 2M x 4N waves, wave tile 128x48
  const int lr = lane & 15, lq = lane >> 4;
  const int m0 = blockIdx.y * 256, n0 = blockIdx.x * 192;
  const int sw0 = (lq ^ (lr & 7)) << 3;  // swizzled k-offset (elems), k-slice 0
  const int sw1 = sw0 ^ 32;              // k-slice 1

  const __hip_bfloat16* Abase = A + (size_t)m0 * K;
  const __hip_bfloat16* Bbase = Bt + (size_t)n0 * K;

  auto stA = [&](int buf, int half, int kk) {
#pragma unroll
    for (int pp = 0; pp < 2; ++pp) {
      int p = half * 2 + pp;
      int idx = p * 512 + tid;
      int row = idx >> 3;
      int lc = (idx & 7) ^ (row & 7);  // inverse-swizzled global chunk for this slot
      gload16(Abase + (size_t)row * K + kk + lc * 8,
              (char*)lds + buf * 57344 + p * 8192 + wv * 1024);
    }
  };
  auto stB2 = [&](int buf, int kk) {
#pragma unroll
    for (int p = 0; p < 2; ++p) {
      int idx = p * 512 + tid;
      int row = idx >> 3;
      int lc = (idx & 7) ^ (row & 7);
      gload16(Bbase + (size_t)row * K + kk + lc * 8,
              (char*)lds + buf * 57344 + 32768 + p * 8192 + wv * 1024);
    }
  };
  auto stB1 = [&](int buf, int kk) {
    int idx = 2 * 512 + tid;
    int row = idx >> 3;
    int lc = (idx & 7) ^ (row & 7);
    gload16(Bbase + (size_t)row * K + kk + lc * 8,
            (char*)lds + buf * 57344 + 49152 + wv * 1024);
  };

  floatx4 acc[8][3] = {};
  short8 afA[4], afB[4], afC[4], afD[4], bfA[3], bfB[3];

  // prologue: batch0 (7 loads, dbuf0, k=0); batch1 A0 (2 loads, dbuf1, k=64)
  stA(0, 0, 0); stA(0, 1, 0); stB2(0, 0); stB1(0, 0);
  stA(1, 0, 64);

#pragma unroll 1
  for (int it = 0; it < 16; ++it) {
    const int t = 2 * it;
    const int kk1 = (t + 1) * 64;
    const int kk2 = (t + 2 < 32) ? (t + 2) * 64 : 0;  // wrap: harmless re-read, uniform counts
    const int kk3 = (t + 3 < 32) ? (t + 3) * 64 : 0;

    // ======== tile t (dbuf0) ========
    S_VMCNT2; S_BAR;
    RD_A4(afA, 0, 0, 0); RD_B3(bfA, 0, 0);
    stA(1, 1, kk1);
    S_LGKM0;
    MFG(afA, bfA, 0);
    S_BAR;
    RD_A4(afB, 0, 1, 0); RD_A4(afC, 0, 0, 1);
    stB2(1, kk1);
    S_LGKM0;
    MFG(afB, bfA, 1);
    S_BAR;
    RD_B3(bfB, 0, 1); RD_A4(afD, 0, 1, 1);
    stB1(1, kk1);
    S_LGKM0;
    MFG(afC, bfB, 0);
    S_BAR;
    stA(0, 0, kk2);
    MFG(afD, bfB, 1);
    S_BAR;

    // ======== tile t+1 (dbuf1) ========
    S_VMCNT2; S_BAR;
    RD_A4(afA, 1, 0, 0); RD_B3(bfA, 1, 0);
    stA(0, 1, kk2);
    S_LGKM0;
    MFG(afA, bfA, 0);
    S_BAR;
    RD_A4(afB, 1, 1, 0); RD_A4(afC, 1, 0, 1);
    stB2(0, kk2);
    S_LGKM0;
    MFG(afB, bfA, 1);
    S_BAR;
    RD_B3(bfB, 1, 1); RD_A4(afD, 1, 1, 1);
    stB1(0, kk2);
    S_LGKM0;
    MFG(afC, bfB, 0);
    S_BAR;
    stA(1, 0, kk3);
    MFG(afD, bfB, 1);
    S_BAR;
  }

  asm volatile("s_waitcnt vmcnt(0)" ::: "memory");
  __builtin_amdgcn_sched_barrier(0);

#pragma unroll
  for (int i = 0; i < 8; ++i)
#pragma unroll
    for (int j = 0; j < 3; ++j)
#pragma unroll
      for (int r = 0; r < 4; ++r) {
        int row = m0 + wm * 128 + i * 16 + lq * 4 + r;
        int col = n0 + wn * 48 + j * 16 + lr;
        Cp[(size_t)row * 6144 + col] = __float2bfloat16(acc[i][j][r]);
      }
}

// ---------------- GEMM2: BM=256, BN=128, BK=64, 3-deep LDS ring (r2/r4-proven, frozen) ----------------
#define S_VMCNT6 do { asm volatile("s_waitcnt vmcnt(6)" ::: "memory"); \
                      __builtin_amdgcn_sched_barrier(0); } while (0)

template <int NCOLS, bool OUT_F32>
__global__ __launch_bounds__(512, 2) void gemm_dp_kernel(
    const __hip_bfloat16* __restrict__ A, const __hip_bfloat16* __restrict__ Bt,
    void* __restrict__ Cp) {
  const int K = 2048, NT = 32;
  __shared__ __hip_bfloat16 lds[3 * 24576];  // 3 x [A 16384 | B 8192] elems
  const int tid = threadIdx.x;
  const int lane = tid & 63, wv = tid >> 6;
  const int wm = wv >> 1, wn = wv & 1;  // 4M x 2N wave grid
  const int lr = lane & 15, lq = lane >> 4;
  const int m0 = blockIdx.y * 256, n0 = blockIdx.x * 128;
  const int sw0 = (lq ^ (lr & 7)) << 3;
  const int sw1 = sw0 ^ 32;

  auto stageA = [&](int bw, int p, int kk) {
    int idx = p * 512 + tid;
    int row = idx >> 3;
    int lc = (idx & 7) ^ (row & 7);
    gload16(A + (size_t)(m0 + row) * K + kk + lc * 8,
            (char*)lds + (size_t)bw * 49152 + (size_t)(p * 512 + wv * 64) * 16);
  };
  auto stageB = [&](int bw, int p, int kk) {
    int idx = p * 512 + tid;
    int row = idx >> 3;
    int lc = (idx & 7) ^ (row & 7);
    gload16(Bt + (size_t)(n0 + row) * K + kk + lc * 8,
            (char*)lds + (size_t)bw * 49152 + 32768 + (size_t)(p * 512 + wv * 64) * 16);
  };

#pragma unroll
  for (int p = 0; p < 4; ++p) stageA(0, p, 0);
#pragma unroll
  for (int p = 0; p < 2; ++p) stageB(0, p, 0);
#pragma unroll
  for (int p = 0; p < 4; ++p) stageA(1, p, 64);
#pragma unroll
  for (int p = 0; p < 2; ++p) stageB(1, p, 64);

  floatx4 acc[4][4] = {};
  int br = 0, bw = 2;

#pragma unroll 1
  for (int t = 0; t < NT; ++t) {
    const int kk2 = (t + 2 < NT) ? (t + 2) * 64 : 0;

    S_VMCNT6;
    S_BAR;

    const __hip_bfloat16* Ab = lds + br * 24576 + (wm * 64 + lr) * 64;
    const __hip_bfloat16* Bb = lds + br * 24576 + 16384 + (wn * 64 + lr) * 64;

    short8 af0[4], bf0[4];
#pragma unroll
    for (int i = 0; i < 4; ++i) af0[i] = *(const short8*)(Ab + i * 1024 + sw0);
#pragma unroll
    for (int j = 0; j < 4; ++j) bf0[j] = *(const short8*)(Bb + j * 1024 + sw0);
    stageA(bw, 0, kk2); stageA(bw, 1, kk2); stageB(bw, 0, kk2);
    S_LGKM0;
    __builtin_amdgcn_s_setprio(1);
#pragma unroll
    for (int i = 0; i < 4; ++i)
#pragma unroll
      for (int j = 0; j < 4; ++j)
        acc[i][j] = __builtin_amdgcn_mfma_f32_16x16x32_bf16(af0[i], bf0[j], acc[i][j], 0, 0, 0);
    __builtin_amdgcn_s_setprio(0);

    short8 af1[4], bf1[4];
#pragma unroll
    for (int i = 0; i < 4; ++i) af1[i] = *(const short8*)(Ab + i * 1024 + sw1);
#pragma unroll
    for (int j = 0; j < 4; ++j) bf1[j] = *(const short8*)(Bb + j * 1024 + sw1);
    stageA(bw, 2, kk2); stageA(bw, 3, kk2); stageB(bw, 1, kk2);
    S_LGKM0;
    __builtin_amdgcn_s_setprio(1);
#pragma unroll
    for (int i = 0; i < 4; ++i)
#pragma unroll
      for (int j = 0; j < 4; ++j)
        acc[i][j] = __builtin_amdgcn_mfma_f32_16x16x32_bf16(af1[i], bf1[j], acc[i][j], 0, 0, 0);
    __builtin_amdgcn_s_setprio(0);

    br = (br == 2) ? 0 : br + 1;
    bw = (bw == 2) ? 0 : bw + 1;
  }

  asm volatile("s_waitcnt vmcnt(0)" ::: "memory");
  __builtin_amdgcn_sched_barrier(0);

#pragma unroll
  for (int i = 0; i < 4; ++i)
#pragma unroll
    for (int j = 0; j < 4; ++j)
#pragma unroll
      for (int r = 0; r < 4; ++r) {
        int row = m0 + wm * 64 + i * 16 + lq * 4 + r;
        int col = n0 + wn * 64 + j * 16 + lr;
        if (OUT_F32)
          ((float*)Cp)[(size_t)row * NCOLS + col] = acc[i][j][r];
        else
          ((__hip_bfloat16*)Cp)[(size_t)row * NCOLS + col] = __float2bfloat16(acc[i][j][r]);
      }
}

// ---------------- fused mid: RoPE (vectorized) + V pre-transpose + transpose Wproj ----------------
__global__ __launch_bounds__(256) void mid_kernel(
    __hip_bfloat16* __restrict__ qkv, __hip_bfloat16* __restrict__ vt,
    const float* __restrict__ Wproj, __hip_bfloat16* __restrict__ WprojT) {
  __shared__ char smem[18432];  // vtrans: 64*144 shorts; transpose: 32*33 floats
  const int bid = blockIdx.x, tid = threadIdx.x;

  if (bid < 2048) {
    // ---- RoPE: q pre-scaled by log2e/sqrt(Dh) for exp2 softmax ----
    int i = bid * 256 + tid;  // 0..524287 = B*S*H*8
    int d8 = (i & 7) << 3;
    int h = (i >> 3) & 15;
    int row = i >> 7;         // 0..4095
    int s = row & (S_ - 1);
    size_t base = (size_t)row * C3 + h * DH + d8;
    short8 k1 = *(const short8*)(qkv + base);
    short8 k2 = *(const short8*)(qkv + base + 64);
    short8 q1 = *(const short8*)(qkv + base + C_);
    short8 q2 = *(const short8*)(qkv + base + C_ + 64);
    short8 ko1, ko2, qo1, qo2;
    const float scale = 0.08838834764831845f * 1.4426950408889634f;  // log2e/sqrt(128)
#pragma unroll
    for (int j = 0; j < 8; ++j) {
      float invf = exp2f((float)(d8 + j) * (-13.287712379549449f / 64.0f));  // 10000^(-d/64)
      float ang = (float)s * invf;
      float sn, c;
      __sincosf(ang, &sn, &c);
      float a = bf2f(k1[j]), b = bf2f(k2[j]);
      ko1[j] = f2bf(a * c - b * sn);
      ko2[j] = f2bf(b * c + a * sn);
      a = bf2f(q1[j]); b = bf2f(q2[j]);
      qo1[j] = f2bf((a * c - b * sn) * scale);
      qo2[j] = f2bf((b * c + a * sn) * scale);
    }
    *(short8*)(qkv + base) = ko1;
    *(short8*)(qkv + base + 64) = ko2;
    *(short8*)(qkv + base + C_) = qo1;
    *(short8*)(qkv + base + C_ + 64) = qo2;
  } else if (bid < 3072) {
    // ---- V pre-transpose ----
    short* T = (short*)smem;  // [s][d], pitch 144 (16B-aligned rows)
    const int t = (bid - 2048) & 31, bh = (bid - 2048) >> 5;
    const int b = bh >> 4, h = bh & 15;
    const size_t brow = (size_t)b * S_;
#pragma unroll
    for (int p = 0; p < 4; ++p) {
      int idx = p * 256 + tid;
      int row = idx >> 4, c8 = idx & 15;
      *(short8*)(T + row * 144 + c8 * 8) =
          *(const short8*)(qkv + (brow + t * 64 + row) * C3 + 2 * C_ + h * DH + c8 * 8);
    }
    __syncthreads();
#pragma unroll
    for (int p = 0; p < 4; ++p) {
      int L = p * 256 + tid;
      int d = L & 127, cs = L >> 7;
      short8 v;
#pragma unroll
      for (int j = 0; j < 8; ++j) v[j] = T[(cs * 8 + j) * 144 + d];
      *(short8*)(vt + ((size_t)bh * 32 + t) * 8192 + (size_t)L * 8) = v;
    }
  } else {
    // ---- transpose Wproj ----
    int tb = bid - 3072;  // 4096 tiles: 64 x 64
    int bx = tb & 63, by = tb >> 6;
    transpose_cast_dev(Wproj, WprojT, 2048, 2048, bx * 32, by * 32, tid,
                       (float(*)[33])smem);
  }
}

// ---------------- Flash attention r8: T12 in-register P + K/V double-buffer, 1 barrier/kt ----------------
// r4 load-balance remap kept (block n and n+256 share a CU, complementary qt -> uniform 34 kt/CU).
// r8 changes vs r7:
//  - Ps LDS buffer ELIMINATED: P^T -> PV-A-operand redistribution done in-register.
//    Derivation: st[rt][t4][r] holds P[q=q0w+rt*16+lr][s=kb+t4*16+lq*4+r]. PV A-frag needs
//    lane(lr,lq) to hold P[q][kb+ks*32+lq*8+j]. With u=lq*8+j: t4_src=2ks+(lq>>1),
//    lq_src=(lq&1)*2+(j>>2), r_src=j&3. So: pack pkL/pkH[rt][t4] = cvt_pk(st[r=0,1]/[r=2,3]),
//    then dword m of pa[rt][ks] = shfl(pk{L,H}[rt][2ks+(lq>>1)], lane=((lq&1)*2+(m>>1))*16+lr).
//    The (lq>>1) T-select is done by shuffling both parities + cndmask.
//  - K/V double-buffered (64 KB total, still 2 blocks/CU = 128 KB): commit(kt+1) writes
//    buf^1 while compute reads buf -> ONE barrier per kt (WAR: buf^1's readers retired at
//    the PREVIOUS iteration's barrier; RAW: barrier at end of kt-1 published buf).
//  - commit's vmcnt dep-waits are covered by the ~2000cy compute phase (true T14 payoff).
__global__ __launch_bounds__(256, 2) void attn_kernel(
    const __hip_bfloat16* __restrict__ qkv,
    const __hip_bfloat16* __restrict__ vt_tiles,
    __hip_bfloat16* __restrict__ outp) {
  __shared__ __hip_bfloat16 Ks[2][8192];  // [buf][64 s x 128 d], xor-swizzled 16B chunks
  __shared__ __hip_bfloat16 Vt[2][8192];  // [buf][chunk L = cs*128 + d] (matches vt_tiles)

  const int tid = threadIdx.x, lane = tid & 63, wv = tid >> 6;
  const int lr = lane & 15, lq = lane >> 4;
  const int n = blockIdx.y * 16 + blockIdx.x;  // dispatch-linear block id
  const int half = n >> 8, rr = n & 255;
  const int bh = rr >> 3, p = rr & 7;
  const int qt = half ? p : 15 - p;            // complementary-weight pairing (r4)
  const int b = bh >> 4, h = bh & 15;
  const int q0w = qt * 128 + wv * 32;
  const size_t brow = (size_t)b * S_;
  const int nkt = 2 * qt + 2;
  const int wrow_last = q0w + 31;

  // Q fragments (B-operand layout): q = q0w + rt*16 + lr, k-chunk lq*8
  short8 qf[2][4];
#pragma unroll
  for (int rt = 0; rt < 2; ++rt)
#pragma unroll
    for (int ks = 0; ks < 4; ++ks)
      qf[rt][ks] = *(const short8*)(qkv + (brow + q0w + rt * 16 + lr) * C3 + C_ + h * DH + ks * 32 + lq * 8);

  // T14 reg-staging: issue-early / write-late
  short8 kreg[4], vreg[4];
  auto issue = [&](int kti) {
    if (kti >= nkt) kti = nkt - 1;  // tail clamp (harmless re-read)
    const int kb = kti * 64;
#pragma unroll
    for (int pp = 0; pp < 4; ++pp) {
      int L = pp * 256 + tid;
      int srow = L >> 4;
      int ck = (L & 15) ^ (srow & 15);
      kreg[pp] = *(const short8*)(qkv + (brow + kb + srow) * C3 + h * DH + ck * 8);
      vreg[pp] = *(const short8*)(vt_tiles + ((size_t)bh * 32 + kti) * 8192 + (size_t)L * 8);
    }
  };
  auto commit = [&](int buf) {
#pragma unroll
    for (int pp = 0; pp < 4; ++pp) {
      *(short8*)(Ks[buf] + (size_t)(pp * 256 + tid) * 8) = kreg[pp];
      *(short8*)(Vt[buf] + (size_t)(pp * 256 + tid) * 8) = vreg[pp];
    }
  };

  floatx4 of[2][8] = {};           // O accum: q = rt*16 + lq*4 + r (rel), d = dt*16 + lr
  float l_run[2] = {0.0f, 0.0f};   // per-lane, q = q0w + rt*16 + lr

  issue(0);
  commit(0);
  __syncthreads();   // tile 0 visible

  for (int kt = 0; kt < nkt; ++kt) {
    const int kb = kt * 64;
    const int buf = kt & 1;
    issue(kt + 1);   // 8 global loads in flight across the whole compute phase

    if (kb <= wrow_last) {  // wave-uniform
      // ---- St = K Q^T : st[rt][t4][r] -> s = kb + t4*16 + lq*4 + r, q = q0w + rt*16 + lr ----
      floatx4 st[2][4] = {};
#pragma unroll
      for (int ks = 0; ks < 4; ++ks) {
        short8 kfr[4];
#pragma unroll
        for (int t4 = 0; t4 < 4; ++t4)
          kfr[t4] = *(const short8*)(Ks[buf] + ((t4 * 16 + lr) * 16 + ((ks * 4 + lq) ^ lr)) * 8);
#pragma unroll
        for (int rt = 0; rt < 2; ++rt)
#pragma unroll
          for (int t4 = 0; t4 < 4; ++t4)
            st[rt][t4] = __builtin_amdgcn_mfma_f32_16x16x32_bf16(kfr[t4], qf[rt][ks], st[rt][t4], 0, 0, 0);
      }

      // ---- causal mask (tiles intersecting this wave's diagonal) ----
      if (kb + 63 > q0w) {
#pragma unroll
        for (int rt = 0; rt < 2; ++rt)
#pragma unroll
          for (int t4 = 0; t4 < 4; ++t4)
#pragma unroll
            for (int r = 0; r < 4; ++r) {
              int s = kb + t4 * 16 + lq * 4 + r;
              if (s > q0w + rt * 16 + lr) st[rt][t4][r] = -1e30f;
            }
      }

      // ---- softmax numerator: p = exp2(s') (s' pre-scaled by log2e), row sums ----
#pragma unroll
      for (int rt = 0; rt < 2; ++rt) {
        float rs = 0.0f;
#pragma unroll
        for (int t4 = 0; t4 < 4; ++t4)
#pragma unroll
          for (int r = 0; r < 4; ++r) {
            float pv = exp2f(st[rt][t4][r]);
            st[rt][t4][r] = pv;
            rs += pv;
          }
        rs += __shfl_xor(rs, 16);
        rs += __shfl_xor(rs, 32);
        l_run[rt] += rs;
      }

      // ---- T12: pack P to bf16 pairs in-register ----
      unsigned pkL[2][4], pkH[2][4];
#pragma unroll
      for (int rt = 0; rt < 2; ++rt)
#pragma unroll
        for (int t4 = 0; t4 < 4; ++t4) {
          pkL[rt][t4] = pk_bf16(st[rt][t4][0], st[rt][t4][1]);
          pkH[rt][t4] = pk_bf16(st[rt][t4][2], st[rt][t4][3]);
        }
      const int s0 = (lq & 1) * 32 + lr;   // lane lq_src=(lq&1)*2, same lr
      const int s1 = s0 + 16;              // lane lq_src=(lq&1)*2+1
      const bool hi = (lq >> 1) != 0;      // T-parity select

      // ---- O += P V (A-operand assembled via shfl) ----
#pragma unroll
      for (int ks = 0; ks < 2; ++ks) {
        short8 pa[2];
#pragma unroll
        for (int rt = 0; rt < 2; ++rt) {
          unsigned aL0 = __shfl(pkL[rt][2 * ks], s0), aL1 = __shfl(pkL[rt][2 * ks + 1], s0);
          unsigned aH0 = __shfl(pkH[rt][2 * ks], s0), aH1 = __shfl(pkH[rt][2 * ks + 1], s0);
          unsigned bL0 = __shfl(pkL[rt][2 * ks], s1), bL1 = __shfl(pkL[rt][2 * ks + 1], s1);
          unsigned bH0 = __shfl(pkH[rt][2 * ks], s1), bH1 = __shfl(pkH[rt][2 * ks + 1], s1);
          union { unsigned u[4]; short8 v; } pu;
          pu.u[0] = hi ? aL1 : aL0;   // j=0,1
          pu.u[1] = hi ? aH1 : aH0;   // j=2,3
          pu.u[2] = hi ? bL1 : bL0;   // j=4,5
          pu.u[3] = hi ? bH1 : bH0;   // j=6,7
          pa[rt] = pu.v;
        }
#pragma unroll
        for (int dt = 0; dt < 8; ++dt) {
          short8 vb = *(const short8*)(Vt[buf] + ((ks * 4 + lq) * 128 + dt * 16 + lr) * 8);
#pragma unroll
          for (int rt = 0; rt < 2; ++rt)
            of[rt][dt] = __builtin_amdgcn_mfma_f32_16x16x32_bf16(pa[rt], vb, of[rt][dt], 0, 0, 0);
        }
      }
    }

    commit(buf ^ 1);   // vmcnt dep-waits covered by compute; writes the buffer whose
                       // readers retired at the PREVIOUS iteration's barrier (WAR-safe)
    __syncthreads();   // publish kt+1, retire kt's reads -- ONE barrier per kt
  }

  // ---- epilogue: O /= l ----
#pragma unroll
  for (int rt = 0; rt < 2; ++rt) {
    float linv = 1.0f / l_run[rt];
    floatx4 lv;
#pragma unroll
    for (int r = 0; r < 4; ++r) lv[r] = __shfl(linv, lq * 4 + r);
#pragma unroll
    for (int dt = 0; dt < 8; ++dt)
#pragma unroll
      for (int r = 0; r < 4; ++r)
        outp[(brow + q0w + rt * 16 + lq * 4 + r) * C_ + h * DH + dt * 16 + lr] =
            __float2bfloat16(of[rt][dt][r] * lv[r]);
  }
}

extern "C" void kernel_launch(void* const* d_in, const int* in_sizes, int n_in,
                              void* d_out, int out_size, void* d_ws, size_t ws_size,
                              hipStream_t stream) {
  const float* x = (const float*)d_in[0];      // [4096][2048]
  const float* Wqkv = (const float*)d_in[1];   // [2048][6144]
  const float* Wproj = (const float*)d_in[2];  // [2048][2048]

  // workspace layout (bf16 elements), with reuse
  __hip_bfloat16* xb = (__hip_bfloat16*)d_ws;              // 4096*2048
  __hip_bfloat16* WqkvT = xb + (size_t)4096 * 2048;        // 6144*2048
  __hip_bfloat16* qkvb = WqkvT + (size_t)6144 * 2048;      // 4096*6144
  __hip_bfloat16* WprojT = WqkvT;                          // 2048*2048 (after GEMM1)
  __hip_bfloat16* vt_tiles = WqkvT + (size_t)2048 * 2048;  // 2*16*32*8192 (after GEMM1)
  __hip_bfloat16* attnb = xb;                              // 4096*2048 (after GEMM1)

  // fused: cast x + transpose Wqkv
  pre_kernel<<<8192 + 12288, 256, 0, stream>>>(x, xb, Wqkv, WqkvT);

  // GEMM1: M=4096, N=6144 -> grid 32x16 = 512 blocks = exactly 2 rounds of 256 CUs
  gemm1_kernel<<<dim3(6144 / 192, 4096 / 256), 512, 0, stream>>>(xb, WqkvT, qkvb);

  // fused: rope + vtrans + transpose Wproj
  mid_kernel<<<2048 + 1024 + 4096, 256, 0, stream>>>(qkvb, vt_tiles, Wproj, WprojT);

  attn_kernel<<<dim3(16, 32), 256, 0, stream>>>(qkvb, vt_tiles, attnb);

  // GEMM2: M=4096, N=2048 -> grid 16x16 = 256 blocks = exactly 1 round
  gemm_dp_kernel<2048, true><<<dim3(2048 / 128, 4096 / 256), 512, 0, stream>>>(
      attnb, WprojT, (float*)d_out);
}

// Round 9
// 336.043 us; speedup vs baseline: 1.0278x; 1.0278x over previous
//
#include <hip/hip_runtime.h>
#include <hip/hip_bf16.h>

// Problem constants
#define B_   2
#define S_   2048
#define C_   2048
#define H_   16
#define DH   128
#define C3   (3 * C_)

typedef __attribute__((ext_vector_type(8))) short short8;
typedef __attribute__((ext_vector_type(4))) float floatx4;

__device__ __forceinline__ void gload16(const void* g, void* l) {
  __builtin_amdgcn_global_load_lds(
      (const __attribute__((address_space(1))) unsigned int*)g,
      (__attribute__((address_space(3))) unsigned int*)l, 16, 0, 0);
}

__device__ __forceinline__ unsigned pk_bf16(float a, float b) {
  union { __hip_bfloat16 h; unsigned short u; } ua, ub;
  ua.h = __float2bfloat16(a); ub.h = __float2bfloat16(b);
  return (unsigned)ua.u | ((unsigned)ub.u << 16);
}

__device__ __forceinline__ float bf2f(short u) {
  union { unsigned u; float f; } t;
  t.u = ((unsigned)(unsigned short)u) << 16;
  return t.f;
}
__device__ __forceinline__ short f2bf(float f) {
  union { __hip_bfloat16 h; short s; } t;
  t.h = __float2bfloat16(f);
  return t.s;
}

// ---------------- transpose + cast, 64-row tiles (r9): in[.][Cc] f32 -> out[.][R] bf16 ----------------
// Tile: in rows r0..r0+63, cols c0..c0+31 -> out rows c0..c0+31 (64 elems = 128B contiguous each).
// Writes are full-HBM-granule (128B per 16 lanes) vs the old 64B segments (2x write amplification).
// LDS banks: load phase coalesced float4; store phase (rq*4+e)*33+oc -> 4rq+e+oc mod 32 = 2-way (free).
__device__ __forceinline__ void transpose_cast_dev64(
    const float* __restrict__ in, __hip_bfloat16* __restrict__ out,
    int R, int Cc, int c0, int r0, int tid, float (*T)[33]) {
#pragma unroll
  for (int pass = 0; pass < 2; ++pass) {
    int row = pass * 32 + (tid >> 3), c4 = tid & 7;
    float4 v = *(const float4*)&in[(size_t)(r0 + row) * Cc + c0 + c4 * 4];
    T[row][c4 * 4 + 0] = v.x;
    T[row][c4 * 4 + 1] = v.y;
    T[row][c4 * 4 + 2] = v.z;
    T[row][c4 * 4 + 3] = v.w;
  }
  __syncthreads();
#pragma unroll
  for (int pass = 0; pass < 2; ++pass) {
    int oc = pass * 16 + (tid >> 4), rq = tid & 15;
    union { __hip_bfloat16 b[4]; uint2 u; } t;
#pragma unroll
    for (int e = 0; e < 4; ++e) t.b[e] = __float2bfloat16(T[rq * 4 + e][oc]);
    *(uint2*)&out[(size_t)(c0 + oc) * R + r0 + rq * 4] = t.u;
  }
}

// ---------------- fused pre: cast x + transpose Wqkv + transpose Wproj (r9: Wproj moved here) ----------------
// blocks [0,8192): cast x; [8192,14336): Wqkv-T (6144 tiles = 192 x 32); [14336,16384): Wproj-T (64 x 32).
// Wproj-T has no dependence on gemm1 -> doing it here shortens the critical-path mid kernel.
__global__ __launch_bounds__(256) void pre_kernel(
    const float* __restrict__ x, __hip_bfloat16* __restrict__ xb,
    const float* __restrict__ Wqkv, __hip_bfloat16* __restrict__ WqkvT,
    const float* __restrict__ Wproj, __hip_bfloat16* __restrict__ WprojT) {
  __shared__ float tile[64][33];
  const int bid = blockIdx.x, tid = threadIdx.x;
  if (bid < 8192) {
    int i = bid * 256 + tid;  // < 2097152 = (4096*2048)/4 exactly
    float4 v = ((const float4*)x)[i];
    union { __hip_bfloat16 b[4]; uint2 u; } t;
    t.b[0] = __float2bfloat16(v.x);
    t.b[1] = __float2bfloat16(v.y);
    t.b[2] = __float2bfloat16(v.z);
    t.b[3] = __float2bfloat16(v.w);
    ((uint2*)xb)[i] = t.u;
  } else if (bid < 14336) {
    int tb = bid - 8192;             // 6144 tiles: 192 (cols) x 32 (row-64s)
    int bx = tb % 192, by = tb / 192;
    transpose_cast_dev64(Wqkv, WqkvT, 2048, 6144, bx * 32, by * 64, tid, tile);
  } else {
    int tb = bid - 14336;            // 2048 tiles: 64 (cols) x 32 (row-64s)
    int bx = tb & 63, by = tb >> 6;
    transpose_cast_dev64(Wproj, WprojT, 2048, 2048, bx * 32, by * 64, tid, tile);
  }
}

// ---------------- sync macros (rule: sched_barrier after every asm wait / barrier) ----------------
#define S_VMCNT2 do { asm volatile("s_waitcnt vmcnt(2)" ::: "memory"); \
                      __builtin_amdgcn_sched_barrier(0); } while (0)
#define S_LGKM0  do { asm volatile("s_waitcnt lgkmcnt(0)" ::: "memory"); \
                      __builtin_amdgcn_sched_barrier(0); } while (0)
#define S_BAR    do { __builtin_amdgcn_s_barrier(); \
                      __builtin_amdgcn_sched_barrier(0); } while (0)

// ---------------- GEMM1: 256x192, BK=64, wave tile 128x48, 8-phase counted-vmcnt ----------------
// FROZEN at the r3/r4-proven structure (96.4 us, MfmaUtil 46, 0 bank conflicts).

#define RD_A4(dst, buf, mh, sl)                                                          \
  do {                                                                                   \
    const __hip_bfloat16* base_ =                                                        \
        lds + (buf) * 28672 + (wm * 128 + (mh) * 64 + lr) * 64 + ((sl) ? sw1 : sw0);     \
    _Pragma("unroll") for (int i_ = 0; i_ < 4; ++i_)                                     \
        dst[i_] = *(const short8*)(base_ + i_ * 1024);                                   \
  } while (0)

#define RD_B3(dst, buf, sl)                                                              \
  do {                                                                                   \
    const __hip_bfloat16* base_ =                                                        \
        lds + (buf) * 28672 + 16384 + (wn * 48 + lr) * 64 + ((sl) ? sw1 : sw0);          \
    _Pragma("unroll") for (int j_ = 0; j_ < 3; ++j_)                                     \
        dst[j_] = *(const short8*)(base_ + j_ * 1024);                                   \
  } while (0)

#define MFG(afp, bfp, mh)                                                                \
  do {                                                                                   \
    __builtin_amdgcn_s_setprio(1);                                                       \
    _Pragma("unroll") for (int i_ = 0; i_ < 4; ++i_)                                     \
    _Pragma("unroll") for (int j_ = 0; j_ < 3; ++j_)                                     \
        acc[(mh) * 4 + i_][j_] = __builtin_amdgcn_mfma_f32_16x16x32_bf16(                \
            afp[i_], bfp[j_], acc[(mh) * 4 + i_][j_], 0, 0, 0);                          \
    __builtin_amdgcn_s_setprio(0);                                                       \
  } while (0)

__global__ __launch_bounds__(512, 2) void gemm1_kernel(
    const __hip_bfloat16* __restrict__ A, const __hip_bfloat16* __restrict__ Bt,
    __hip_bfloat16* __restrict__ Cp) {
  const int K = 2048;
  __shared__ __hip_bfloat16 lds[2 * 28672];  // 2 x (A 16384 + B 12288) elems
  const int tid = threadIdx.x;
  const int lane = tid & 63, wv = tid >> 6;
  const int wm = wv >> 2, wn = wv & 3;  // 2M x 4N waves, wave tile 128x48
  const int lr = lane & 15, lq = lane >> 4;
  const int m0 = blockIdx.y * 256, n0 = blockIdx.x * 192;
  const int sw0 = (lq ^ (lr & 7)) << 3;  // swizzled k-offset (elems), k-slice 0
  const int sw1 = sw0 ^ 32;              // k-slice 1

  const __hip_bfloat16* Abase = A + (size_t)m0 * K;
  const __hip_bfloat16* Bbase = Bt + (size_t)n0 * K;

  auto stA = [&](int buf, int half, int kk) {
#pragma unroll
    for (int pp = 0; pp < 2; ++pp) {
      int p = half * 2 + pp;
      int idx = p * 512 + tid;
      int row = idx >> 3;
      int lc = (idx & 7) ^ (row & 7);  // inverse-swizzled global chunk for this slot
      gload16(Abase + (size_t)row * K + kk + lc * 8,
              (char*)lds + buf * 57344 + p * 8192 + wv * 1024);
    }
  };
  auto stB2 = [&](int buf, int kk) {
#pragma unroll
    for (int p = 0; p < 2; ++p) {
      int idx = p * 512 + tid;
      int row = idx >> 3;
      int lc = (idx & 7) ^ (row & 7);
      gload16(Bbase + (size_t)row * K + kk + lc * 8,
              (char*)lds + buf * 57344 + 32768 + p * 8192 + wv * 1024);
    }
  };
  auto stB1 = [&](int buf, int kk) {
    int idx = 2 * 512 + tid;
    int row = idx >> 3;
    int lc = (idx & 7) ^ (row & 7);
    gload16(Bbase + (size_t)row * K + kk + lc * 8,
            (char*)lds + buf * 57344 + 49152 + wv * 1024);
  };

  floatx4 acc[8][3] = {};
  short8 afA[4], afB[4], afC[4], afD[4], bfA[3], bfB[3];

  // prologue: batch0 (7 loads, dbuf0, k=0); batch1 A0 (2 loads, dbuf1, k=64)
  stA(0, 0, 0); stA(0, 1, 0); stB2(0, 0); stB1(0, 0);
  stA(1, 0, 64);

#pragma unroll 1
  for (int it = 0; it < 16; ++it) {
    const int t = 2 * it;
    const int kk1 = (t + 1) * 64;
    const int kk2 = (t + 2 < 32) ? (t + 2) * 64 : 0;  // wrap: harmless re-read, uniform counts
    const int kk3 = (t + 3 < 32) ? (t + 3) * 64 : 0;

    // ======== tile t (dbuf0) ========
    S_VMCNT2; S_BAR;
    RD_A4(afA, 0, 0, 0); RD_B3(bfA, 0, 0);
    stA(1, 1, kk1);
    S_LGKM0;
    MFG(afA, bfA, 0);
    S_BAR;
    RD_A4(afB, 0, 1, 0); RD_A4(afC, 0, 0, 1);
    stB2(1, kk1);
    S_LGKM0;
    MFG(afB, bfA, 1);
    S_BAR;
    RD_B3(bfB, 0, 1); RD_A4(afD, 0, 1, 1);
    stB1(1, kk1);
    S_LGKM0;
    MFG(afC, bfB, 0);
    S_BAR;
    stA(0, 0, kk2);
    MFG(afD, bfB, 1);
    S_BAR;

    // ======== tile t+1 (dbuf1) ========
    S_VMCNT2; S_BAR;
    RD_A4(afA, 1, 0, 0); RD_B3(bfA, 1, 0);
    stA(0, 1, kk2);
    S_LGKM0;
    MFG(afA, bfA, 0);
    S_BAR;
    RD_A4(afB, 1, 1, 0); RD_A4(afC, 1, 0, 1);
    stB2(0, kk2);
    S_LGKM0;
    MFG(afB, bfA, 1);
    S_BAR;
    RD_B3(bfB, 1, 1); RD_A4(afD, 1, 1, 1);
    stB1(0, kk2);
    S_LGKM0;
    MFG(afC, bfB, 0);
    S_BAR;
    stA(1, 0, kk3);
    MFG(afD, bfB, 1);
    S_BAR;
  }

  asm volatile("s_waitcnt vmcnt(0)" ::: "memory");
  __builtin_amdgcn_sched_barrier(0);

#pragma unroll
  for (int i = 0; i < 8; ++i)
#pragma unroll
    for (int j = 0; j < 3; ++j)
#pragma unroll
      for (int r = 0; r < 4; ++r) {
        int row = m0 + wm * 128 + i * 16 + lq * 4 + r;
        int col = n0 + wn * 48 + j * 16 + lr;
        Cp[(size_t)row * 6144 + col] = __float2bfloat16(acc[i][j][r]);
      }
}

// ---------------- GEMM2: BM=256, BN=128, BK=64, 3-deep LDS ring (r2/r4-proven, frozen) ----------------
#define S_VMCNT6 do { asm volatile("s_waitcnt vmcnt(6)" ::: "memory"); \
                      __builtin_amdgcn_sched_barrier(0); } while (0)

template <int NCOLS, bool OUT_F32>
__global__ __launch_bounds__(512, 2) void gemm_dp_kernel(
    const __hip_bfloat16* __restrict__ A, const __hip_bfloat16* __restrict__ Bt,
    void* __restrict__ Cp) {
  const int K = 2048, NT = 32;
  __shared__ __hip_bfloat16 lds[3 * 24576];  // 3 x [A 16384 | B 8192] elems
  const int tid = threadIdx.x;
  const int lane = tid & 63, wv = tid >> 6;
  const int wm = wv >> 1, wn = wv & 1;  // 4M x 2N wave grid
  const int lr = lane & 15, lq = lane >> 4;
  const int m0 = blockIdx.y * 256, n0 = blockIdx.x * 128;
  const int sw0 = (lq ^ (lr & 7)) << 3;
  const int sw1 = sw0 ^ 32;

  auto stageA = [&](int bw, int p, int kk) {
    int idx = p * 512 + tid;
    int row = idx >> 3;
    int lc = (idx & 7) ^ (row & 7);
    gload16(A + (size_t)(m0 + row) * K + kk + lc * 8,
            (char*)lds + (size_t)bw * 49152 + (size_t)(p * 512 + wv * 64) * 16);
  };
  auto stageB = [&](int bw, int p, int kk) {
    int idx = p * 512 + tid;
    int row = idx >> 3;
    int lc = (idx & 7) ^ (row & 7);
    gload16(Bt + (size_t)(n0 + row) * K + kk + lc * 8,
            (char*)lds + (size_t)bw * 49152 + 32768 + (size_t)(p * 512 + wv * 64) * 16);
  };

#pragma unroll
  for (int p = 0; p < 4; ++p) stageA(0, p, 0);
#pragma unroll
  for (int p = 0; p < 2; ++p) stageB(0, p, 0);
#pragma unroll
  for (int p = 0; p < 4; ++p) stageA(1, p, 64);
#pragma unroll
  for (int p = 0; p < 2; ++p) stageB(1, p, 64);

  floatx4 acc[4][4] = {};
  int br = 0, bw = 2;

#pragma unroll 1
  for (int t = 0; t < NT; ++t) {
    const int kk2 = (t + 2 < NT) ? (t + 2) * 64 : 0;

    S_VMCNT6;
    S_BAR;

    const __hip_bfloat16* Ab = lds + br * 24576 + (wm * 64 + lr) * 64;
    const __hip_bfloat16* Bb = lds + br * 24576 + 16384 + (wn * 64 + lr) * 64;

    short8 af0[4], bf0[4];
#pragma unroll
    for (int i = 0; i < 4; ++i) af0[i] = *(const short8*)(Ab + i * 1024 + sw0);
#pragma unroll
    for (int j = 0; j < 4; ++j) bf0[j] = *(const short8*)(Bb + j * 1024 + sw0);
    stageA(bw, 0, kk2); stageA(bw, 1, kk2); stageB(bw, 0, kk2);
    S_LGKM0;
    __builtin_amdgcn_s_setprio(1);
#pragma unroll
    for (int i = 0; i < 4; ++i)
#pragma unroll
      for (int j = 0; j < 4; ++j)
        acc[i][j] = __builtin_amdgcn_mfma_f32_16x16x32_bf16(af0[i], bf0[j], acc[i][j], 0, 0, 0);
    __builtin_amdgcn_s_setprio(0);

    short8 af1[4], bf1[4];
#pragma unroll
    for (int i = 0; i < 4; ++i) af1[i] = *(const short8*)(Ab + i * 1024 + sw1);
#pragma unroll
    for (int j = 0; j < 4; ++j) bf1[j] = *(const short8*)(Bb + j * 1024 + sw1);
    stageA(bw, 2, kk2); stageA(bw, 3, kk2); stageB(bw, 1, kk2);
    S_LGKM0;
    __builtin_amdgcn_s_setprio(1);
#pragma unroll
    for (int i = 0; i < 4; ++i)
#pragma unroll
      for (int j = 0; j < 4; ++j)
        acc[i][j] = __builtin_amdgcn_mfma_f32_16x16x32_bf16(af1[i], bf1[j], acc[i][j], 0, 0, 0);
    __builtin_amdgcn_s_setprio(0);

    br = (br == 2) ? 0 : br + 1;
    bw = (bw == 2) ? 0 : bw + 1;
  }

  asm volatile("s_waitcnt vmcnt(0)" ::: "memory");
  __builtin_amdgcn_sched_barrier(0);

#pragma unroll
  for (int i = 0; i < 4; ++i)
#pragma unroll
    for (int j = 0; j < 4; ++j)
#pragma unroll
      for (int r = 0; r < 4; ++r) {
        int row = m0 + wm * 64 + i * 16 + lq * 4 + r;
        int col = n0 + wn * 64 + j * 16 + lr;
        if (OUT_F32)
          ((float*)Cp)[(size_t)row * NCOLS + col] = acc[i][j][r];
        else
          ((__hip_bfloat16*)Cp)[(size_t)row * NCOLS + col] = __float2bfloat16(acc[i][j][r]);
      }
}

// ---------------- fused mid (r9): RoPE (vectorized) + V pre-transpose only ----------------
__global__ __launch_bounds__(256) void mid_kernel(
    __hip_bfloat16* __restrict__ qkv, __hip_bfloat16* __restrict__ vt) {
  __shared__ short T[64 * 144];  // vtrans staging, pitch 144 (16B-aligned rows)
  const int bid = blockIdx.x, tid = threadIdx.x;

  if (bid < 2048) {
    // ---- RoPE: q pre-scaled by log2e/sqrt(Dh) for exp2 softmax ----
    int i = bid * 256 + tid;  // 0..524287 = B*S*H*8
    int d8 = (i & 7) << 3;
    int h = (i >> 3) & 15;
    int row = i >> 7;         // 0..4095
    int s = row & (S_ - 1);
    size_t base = (size_t)row * C3 + h * DH + d8;
    short8 k1 = *(const short8*)(qkv + base);
    short8 k2 = *(const short8*)(qkv + base + 64);
    short8 q1 = *(const short8*)(qkv + base + C_);
    short8 q2 = *(const short8*)(qkv + base + C_ + 64);
    short8 ko1, ko2, qo1, qo2;
    const float scale = 0.08838834764831845f * 1.4426950408889634f;  // log2e/sqrt(128)
#pragma unroll
    for (int j = 0; j < 8; ++j) {
      float invf = exp2f((float)(d8 + j) * (-13.287712379549449f / 64.0f));  // 10000^(-d/64)
      float ang = (float)s * invf;
      float sn, c;
      __sincosf(ang, &sn, &c);
      float a = bf2f(k1[j]), b = bf2f(k2[j]);
      ko1[j] = f2bf(a * c - b * sn);
      ko2[j] = f2bf(b * c + a * sn);
      a = bf2f(q1[j]); b = bf2f(q2[j]);
      qo1[j] = f2bf((a * c - b * sn) * scale);
      qo2[j] = f2bf((b * c + a * sn) * scale);
    }
    *(short8*)(qkv + base) = ko1;
    *(short8*)(qkv + base + 64) = ko2;
    *(short8*)(qkv + base + C_) = qo1;
    *(short8*)(qkv + base + C_ + 64) = qo2;
  } else {
    // ---- V pre-transpose ----
    const int t = (bid - 2048) & 31, bh = (bid - 2048) >> 5;
    const int b = bh >> 4, h = bh & 15;
    const size_t brow = (size_t)b * S_;
#pragma unroll
    for (int p = 0; p < 4; ++p) {
      int idx = p * 256 + tid;
      int row = idx >> 4, c8 = idx & 15;
      *(short8*)(T + row * 144 + c8 * 8) =
          *(const short8*)(qkv + (brow + t * 64 + row) * C3 + 2 * C_ + h * DH + c8 * 8);
    }
    __syncthreads();
#pragma unroll
    for (int p = 0; p < 4; ++p) {
      int L = p * 256 + tid;
      int d = L & 127, cs = L >> 7;
      short8 v;
#pragma unroll
      for (int j = 0; j < 8; ++j) v[j] = T[(cs * 8 + j) * 144 + d];
      *(short8*)(vt + ((size_t)bh * 32 + t) * 8192 + (size_t)L * 8) = v;
    }
  }
}

// ---------------- Flash attention r9: r8 + V-LDS XOR swizzle (kills the 4-way PV read conflict) ----------------
// Counter evidence: r3's attn showed SQ_LDS_BANK_CONFLICT = 1.6M -- the only nonzero kernel.
// Bank derivation of the surviving V-read: lanes lq=0..3 at byte stride 2048 == 0 mod (32 banks)
// -> every PV V-read b128 was a 4-way conflict. Fix (both-sides rule): chunk L stored at
// L ^ ((L>>7)&7); read pos = cs*128 + dt*16 + (lr ^ (cs&7)). Read classes: 8 lanes / 4-bank
// group = 2-way (free); write: per-wave permuted-contiguous 1KB (free). K path unchanged (2-way).
__global__ __launch_bounds__(256, 2) void attn_kernel(
    const __hip_bfloat16* __restrict__ qkv,
    const __hip_bfloat16* __restrict__ vt_tiles,
    __hip_bfloat16* __restrict__ outp) {
  __shared__ __hip_bfloat16 Ks[2][8192];  // [buf][64 s x 128 d], xor-swizzled via global source
  __shared__ __hip_bfloat16 Vt[2][8192];  // [buf][chunk L ^ ((L>>7)&7)]

  const int tid = threadIdx.x, lane = tid & 63, wv = tid >> 6;
  const int lr = lane & 15, lq = lane >> 4;
  const int n = blockIdx.y * 16 + blockIdx.x;  // dispatch-linear block id
  const int half = n >> 8, rr = n & 255;
  const int bh = rr >> 3, p = rr & 7;
  const int qt = half ? p : 15 - p;            // complementary-weight pairing (r4)
  const int b = bh >> 4, h = bh & 15;
  const int q0w = qt * 128 + wv * 32;
  const size_t brow = (size_t)b * S_;
  const int nkt = 2 * qt + 2;
  const int wrow_last = q0w + 31;

  // Q fragments (B-operand layout): q = q0w + rt*16 + lr, k-chunk lq*8
  short8 qf[2][4];
#pragma unroll
  for (int rt = 0; rt < 2; ++rt)
#pragma unroll
    for (int ks = 0; ks < 4; ++ks)
      qf[rt][ks] = *(const short8*)(qkv + (brow + q0w + rt * 16 + lr) * C3 + C_ + h * DH + ks * 32 + lq * 8);

  // T14 reg-staging: issue-early / write-late
  short8 kreg[4], vreg[4];
  auto issue = [&](int kti) {
    if (kti >= nkt) kti = nkt - 1;  // tail clamp (harmless re-read)
    const int kb = kti * 64;
#pragma unroll
    for (int pp = 0; pp < 4; ++pp) {
      int L = pp * 256 + tid;
      int srow = L >> 4;
      int ck = (L & 15) ^ (srow & 15);
      kreg[pp] = *(const short8*)(qkv + (brow + kb + srow) * C3 + h * DH + ck * 8);
      vreg[pp] = *(const short8*)(vt_tiles + ((size_t)bh * 32 + kti) * 8192 + (size_t)L * 8);
    }
  };
  auto commit = [&](int buf) {
#pragma unroll
    for (int pp = 0; pp < 4; ++pp) {
      int Lw = pp * 256 + tid;
      int pw = Lw ^ ((Lw >> 7) & 7);  // V chunk swizzle (involution with read side)
      *(short8*)(Ks[buf] + (size_t)Lw * 8) = kreg[pp];
      *(short8*)(Vt[buf] + (size_t)pw * 8) = vreg[pp];
    }
  };

  floatx4 of[2][8] = {};           // O accum: q = rt*16 + lq*4 + r (rel), d = dt*16 + lr
  float l_run[2] = {0.0f, 0.0f};   // per-lane, q = q0w + rt*16 + lr

  issue(0);
  commit(0);
  __syncthreads();   // tile 0 visible

  for (int kt = 0; kt < nkt; ++kt) {
    const int kb = kt * 64;
    const int buf = kt & 1;
    issue(kt + 1);   // 8 global loads in flight across the whole compute phase

    if (kb <= wrow_last) {  // wave-uniform
      // ---- St = K Q^T : st[rt][t4][r] -> s = kb + t4*16 + lq*4 + r, q = q0w + rt*16 + lr ----
      floatx4 st[2][4] = {};
#pragma unroll
      for (int ks = 0; ks < 4; ++ks) {
        short8 kfr[4];
#pragma unroll
        for (int t4 = 0; t4 < 4; ++t4)
          kfr[t4] = *(const short8*)(Ks[buf] + ((t4 * 16 + lr) * 16 + ((ks * 4 + lq) ^ lr)) * 8);
#pragma unroll
        for (int rt = 0; rt < 2; ++rt)
#pragma unroll
          for (int t4 = 0; t4 < 4; ++t4)
            st[rt][t4] = __builtin_amdgcn_mfma_f32_16x16x32_bf16(kfr[t4], qf[rt][ks], st[rt][t4], 0, 0, 0);
      }

      // ---- causal mask (tiles intersecting this wave's diagonal) ----
      if (kb + 63 > q0w) {
#pragma unroll
        for (int rt = 0; rt < 2; ++rt)
#pragma unroll
          for (int t4 = 0; t4 < 4; ++t4)
#pragma unroll
            for (int r = 0; r < 4; ++r) {
              int s = kb + t4 * 16 + lq * 4 + r;
              if (s > q0w + rt * 16 + lr) st[rt][t4][r] = -1e30f;
            }
      }

      // ---- softmax numerator: p = exp2(s') (s' pre-scaled by log2e), row sums ----
#pragma unroll
      for (int rt = 0; rt < 2; ++rt) {
        float rs = 0.0f;
#pragma unroll
        for (int t4 = 0; t4 < 4; ++t4)
#pragma unroll
          for (int r = 0; r < 4; ++r) {
            float pv = exp2f(st[rt][t4][r]);
            st[rt][t4][r] = pv;
            rs += pv;
          }
        rs += __shfl_xor(rs, 16);
        rs += __shfl_xor(rs, 32);
        l_run[rt] += rs;
      }

      // ---- T12: pack P to bf16 pairs in-register ----
      unsigned pkL[2][4], pkH[2][4];
#pragma unroll
      for (int rt = 0; rt < 2; ++rt)
#pragma unroll
        for (int t4 = 0; t4 < 4; ++t4) {
          pkL[rt][t4] = pk_bf16(st[rt][t4][0], st[rt][t4][1]);
          pkH[rt][t4] = pk_bf16(st[rt][t4][2], st[rt][t4][3]);
        }
      const int s0 = (lq & 1) * 32 + lr;   // lane lq_src=(lq&1)*2, same lr
      const int s1 = s0 + 16;              // lane lq_src=(lq&1)*2+1
      const bool hi = (lq >> 1) != 0;      // T-parity select

      // ---- O += P V (A-operand assembled via shfl; V read de-conflicted) ----
#pragma unroll
      for (int ks = 0; ks < 2; ++ks) {
        short8 pa[2];
#pragma unroll
        for (int rt = 0; rt < 2; ++rt) {
          unsigned aL0 = __shfl(pkL[rt][2 * ks], s0), aL1 = __shfl(pkL[rt][2 * ks + 1], s0);
          unsigned aH0 = __shfl(pkH[rt][2 * ks], s0), aH1 = __shfl(pkH[rt][2 * ks + 1], s0);
          unsigned bL0 = __shfl(pkL[rt][2 * ks], s1), bL1 = __shfl(pkL[rt][2 * ks + 1], s1);
          unsigned bH0 = __shfl(pkH[rt][2 * ks], s1), bH1 = __shfl(pkH[rt][2 * ks + 1], s1);
          union { unsigned u[4]; short8 v; } pu;
          pu.u[0] = hi ? aL1 : aL0;   // j=0,1
          pu.u[1] = hi ? aH1 : aH0;   // j=2,3
          pu.u[2] = hi ? bL1 : bL0;   // j=4,5
          pu.u[3] = hi ? bH1 : bH0;   // j=6,7
          pa[rt] = pu.v;
        }
        const int cs = ks * 4 + lq;
        const int vx = lr ^ (cs & 7);   // de-conflict: matches commit's L^((L>>7)&7)
#pragma unroll
        for (int dt = 0; dt < 8; ++dt) {
          short8 vb = *(const short8*)(Vt[buf] + (cs * 128 + dt * 16 + vx) * 8);
#pragma unroll
          for (int rt = 0; rt < 2; ++rt)
            of[rt][dt] = __builtin_amdgcn_mfma_f32_16x16x32_bf16(pa[rt], vb, of[rt][dt], 0, 0, 0);
        }
      }
    }

    commit(buf ^ 1);   // vmcnt dep-waits covered by compute; WAR-safe (prev barrier retired readers)
    __syncthreads();   // publish kt+1, retire kt's reads -- ONE barrier per kt
  }

  // ---- epilogue: O /= l ----
#pragma unroll
  for (int rt = 0; rt < 2; ++rt) {
    float linv = 1.0f / l_run[rt];
    floatx4 lv;
#pragma unroll
    for (int r = 0; r < 4; ++r) lv[r] = __shfl(linv, lq * 4 + r);
#pragma unroll
    for (int dt = 0; dt < 8; ++dt)
#pragma unroll
      for (int r = 0; r < 4; ++r)
        outp[(brow + q0w + rt * 16 + lq * 4 + r) * C_ + h * DH + dt * 16 + lr] =
            __float2bfloat16(of[rt][dt][r] * lv[r]);
  }
}

extern "C" void kernel_launch(void* const* d_in, const int* in_sizes, int n_in,
                              void* d_out, int out_size, void* d_ws, size_t ws_size,
                              hipStream_t stream) {
  const float* x = (const float*)d_in[0];      // [4096][2048]
  const float* Wqkv = (const float*)d_in[1];   // [2048][6144]
  const float* Wproj = (const float*)d_in[2];  // [2048][2048]

  // workspace layout (bf16 elements)
  __hip_bfloat16* xb = (__hip_bfloat16*)d_ws;              // 4096*2048
  __hip_bfloat16* WqkvT = xb + (size_t)4096 * 2048;        // 6144*2048
  __hip_bfloat16* qkvb = WqkvT + (size_t)6144 * 2048;      // 4096*6144
  __hip_bfloat16* WprojT = qkvb + (size_t)4096 * 6144;     // 2048*2048 (r9: written in pre, so own slot)
  __hip_bfloat16* vt_tiles = WqkvT;                        // 2*16*32*8192 (WqkvT dead after gemm1)
  __hip_bfloat16* attnb = xb;                              // 4096*2048 (xb dead after gemm1)

  // fused: cast x + transpose Wqkv + transpose Wproj
  pre_kernel<<<16384, 256, 0, stream>>>(x, xb, Wqkv, WqkvT, Wproj, WprojT);

  // GEMM1: M=4096, N=6144 -> grid 32x16 = 512 blocks = exactly 2 rounds of 256 CUs
  gemm1_kernel<<<dim3(6144 / 192, 4096 / 256), 512, 0, stream>>>(xb, WqkvT, qkvb);

  // fused: rope + vtrans
  mid_kernel<<<2048 + 1024, 256, 0, stream>>>(qkvb, vt_tiles);

  attn_kernel<<<dim3(16, 32), 256, 0, stream>>>(qkvb, vt_tiles, attnb);

  // GEMM2: M=4096, N=2048 -> grid 16x16 = 256 blocks = exactly 1 round
  gemm_dp_kernel<2048, true><<<dim3(2048 / 128, 4096 / 256), 512, 0, stream>>>(
      attnb, WprojT, (float*)d_out);
}